// Round 1
// baseline (396.570 us; speedup 1.0000x reference)
//
#include <hip/hip_runtime.h>

// JPEG encode: (512,3,128,128) fp32 -> two (256,512,192) fp32 outputs.
// One thread per 8x8 block; tid = n*1536 + (b*3+c) so output addr = out + tid*64
// (perfectly contiguous writes). DCT matrix + quant table hardcoded constexpr.

namespace {

constexpr int OUT1 = 512 * 3 * 256 * 64;  // 25165824 elements per output

// 0.5*cos(k*(2m+1)*pi/16) magnitudes (orthonormal DCT-II, fp32-rounded)
constexpr float A0 = 0.35355339059327379f;   // sqrt(1/8)
constexpr float C1 = 0.49039264020161522f;
constexpr float C2 = 0.46193976625564337f;
constexpr float C3 = 0.41573480615127262f;
constexpr float C5 = 0.27778511650980109f;
constexpr float C6 = 0.19134171618254489f;
constexpr float C7 = 0.097545161008064135f;

__device__ constexpr float Dm[8][8] = {
  { A0,  A0,  A0,  A0,  A0,  A0,  A0,  A0},
  { C1,  C3,  C5,  C7, -C7, -C5, -C3, -C1},
  { C2,  C6, -C6, -C2, -C2, -C6,  C6,  C2},
  { C3, -C7, -C1, -C5,  C5,  C1,  C7, -C3},
  { A0, -A0, -A0,  A0,  A0, -A0, -A0,  A0},
  { C5, -C1,  C7,  C3, -C3, -C7,  C1, -C5},
  { C6, -C2,  C2, -C6, -C6,  C2, -C2,  C6},
  { C7, -C5,  C3, -C1,  C1, -C3,  C5, -C7},
};

__device__ constexpr int ZZ[64] = {
   0, 1, 8,16, 9, 2, 3,10,
  17,24,32,25,18,11, 4, 5,
  12,19,26,33,40,48,41,34,
  27,20,13, 6, 7,14,21,28,
  35,42,49,56,57,50,43,36,
  29,22,15,23,30,37,44,51,
  58,59,52,45,38,31,39,46,
  53,60,61,54,47,55,62,63};

__device__ constexpr float Qm[64] = {
  16,11,10,16,24,40,51,61,
  12,12,14,19,26,58,60,55,
  14,13,16,24,40,57,69,56,
  14,17,22,29,51,87,80,62,
  18,22,37,56,68,109,103,77,
  24,35,55,64,81,104,113,92,
  49,64,78,87,103,121,120,101,
  72,92,95,98,112,100,103,99};

__device__ __forceinline__ float4 ld4(const float* p) {
  return *reinterpret_cast<const float4*>(p);
}

}  // namespace

__global__ __launch_bounds__(256) void jpeg_enc(const float* __restrict__ img,
                                                float* __restrict__ out) {
  const unsigned tid = blockIdx.x * 256u + threadIdx.x;
  const unsigned n  = tid / 1536u;        // block index (by*16+bx), 0..255
  const unsigned bc = tid - n * 1536u;    // b*3 + c, 0..1535
  const unsigned by = n >> 4u, bx = n & 15u;

  const float* src = img + (size_t)bc * 16384u + (size_t)by * 1024u + bx * 8u;

  // Load 8x8 patch, subtract 128
  float X[8][8];
#pragma unroll
  for (int r = 0; r < 8; ++r) {
    float4 a = ld4(src + r * 128);
    float4 b = ld4(src + r * 128 + 4);
    X[r][0] = a.x - 128.0f; X[r][1] = a.y - 128.0f;
    X[r][2] = a.z - 128.0f; X[r][3] = a.w - 128.0f;
    X[r][4] = b.x - 128.0f; X[r][5] = b.y - 128.0f;
    X[r][6] = b.z - 128.0f; X[r][7] = b.w - 128.0f;
  }

  // T = D @ X
  float T[8][8];
#pragma unroll
  for (int i = 0; i < 8; ++i) {
#pragma unroll
    for (int l = 0; l < 8; ++l) {
      float s = Dm[i][0] * X[0][l];
#pragma unroll
      for (int k = 1; k < 8; ++k) s = fmaf(Dm[i][k], X[k][l], s);
      T[i][l] = s;
    }
  }

  // Y = T @ D^T  (Y[i][j] = sum_l T[i][l] * Dm[j][l])
  float Y[64];
#pragma unroll
  for (int i = 0; i < 8; ++i) {
#pragma unroll
    for (int j = 0; j < 8; ++j) {
      float s = T[i][0] * Dm[j][0];
#pragma unroll
      for (int l = 1; l < 8; ++l) s = fmaf(T[i][l], Dm[j][l], s);
      Y[i * 8 + j] = s;
    }
  }

  // Zigzag + quantize, fully contiguous writes: out0/out1 chunk = tid*64
  float* o0 = out + (size_t)tid * 64u;
  float* o1 = o0 + OUT1;
#pragma unroll
  for (int i = 0; i < 16; ++i) {
    const int j0 = ZZ[4 * i + 0], j1 = ZZ[4 * i + 1];
    const int j2 = ZZ[4 * i + 2], j3 = ZZ[4 * i + 3];
    const float y0 = Y[j0], y1 = Y[j1], y2 = Y[j2], y3 = Y[j3];
    float4 vq;
    vq.x = rintf(y0 * (1.0f / Qm[j0]));
    vq.y = rintf(y1 * (1.0f / Qm[j1]));
    vq.z = rintf(y2 * (1.0f / Qm[j2]));
    vq.w = rintf(y3 * (1.0f / Qm[j3]));
    float4 vn = make_float4(y0, y1, y2, y3);
    *reinterpret_cast<float4*>(o0 + 4 * i) = vq;
    *reinterpret_cast<float4*>(o1 + 4 * i) = vn;
  }
}

extern "C" void kernel_launch(void* const* d_in, const int* in_sizes, int n_in,
                              void* d_out, int out_size, void* d_ws, size_t ws_size,
                              hipStream_t stream) {
  const float* img = (const float*)d_in[0];
  float* out = (float*)d_out;
  // 393216 blocks total, one thread each: 1536 workgroups x 256 threads
  jpeg_enc<<<dim3(1536), dim3(256), 0, stream>>>(img, out);
}

// Round 2
// 285.230 us; speedup vs baseline: 1.3904x; 1.3904x over previous
//
#include <hip/hip_runtime.h>

// JPEG encode: (512,3,128,128) fp32 -> two (256,512,192) fp32 outputs.
// Workgroup = 256 threads = one block-row (by, bx 0..15) x 16 consecutive bc.
//   Reads:  lane-contiguous in bx -> 4 x 512B segments per load instr (no LDS).
//   Writes: staged through 32KB XOR-swizzled LDS, drained as 1KB/wave
//           contiguous float4 stores (all full cache lines).

namespace {

constexpr int OUT1 = 512 * 3 * 256 * 64;  // 25165824 elements per output

constexpr float A0 = 0.35355339059327379f;   // sqrt(1/8)
constexpr float C1 = 0.49039264020161522f;
constexpr float C2 = 0.46193976625564337f;
constexpr float C3 = 0.41573480615127262f;
constexpr float C5 = 0.27778511650980109f;
constexpr float C6 = 0.19134171618254489f;
constexpr float C7 = 0.097545161008064135f;

__device__ constexpr float Dm[8][8] = {
  { A0,  A0,  A0,  A0,  A0,  A0,  A0,  A0},
  { C1,  C3,  C5,  C7, -C7, -C5, -C3, -C1},
  { C2,  C6, -C6, -C2, -C2, -C6,  C6,  C2},
  { C3, -C7, -C1, -C5,  C5,  C1,  C7, -C3},
  { A0, -A0, -A0,  A0,  A0, -A0, -A0,  A0},
  { C5, -C1,  C7,  C3, -C3, -C7,  C1, -C5},
  { C6, -C2,  C2, -C6, -C6,  C2, -C2,  C6},
  { C7, -C5,  C3, -C1,  C1, -C3,  C5, -C7},
};

__device__ constexpr int ZZ[64] = {
   0, 1, 8,16, 9, 2, 3,10,
  17,24,32,25,18,11, 4, 5,
  12,19,26,33,40,48,41,34,
  27,20,13, 6, 7,14,21,28,
  35,42,49,56,57,50,43,36,
  29,22,15,23,30,37,44,51,
  58,59,52,45,38,31,39,46,
  53,60,61,54,47,55,62,63};

__device__ constexpr float Qm[64] = {
  16,11,10,16,24,40,51,61,
  12,12,14,19,26,58,60,55,
  14,13,16,24,40,57,69,56,
  14,17,22,29,51,87,80,62,
  18,22,37,56,68,109,103,77,
  24,35,55,64,81,104,113,92,
  49,64,78,87,103,121,120,101,
  72,92,95,98,112,100,103,99};

__device__ __forceinline__ float4 ld4(const float* p) {
  return *reinterpret_cast<const float4*>(p);
}

}  // namespace

// Stage one half (32 floats/thread) of one output into LDS, then drain as
// fully-coalesced float4 stores. QUANT/C4 are compile-time.
template <bool QUANT, int C4>
__device__ __forceinline__ void stage_and_drain(
    const float (&Y)[64], float4* smem, float* __restrict__ outBase,
    int t, int bx, int bcL, int by, int bc0) {
#pragma unroll
  for (int i8 = 0; i8 < 8; ++i8) {
    const int i = C4 * 8 + i8;
    const int j0 = ZZ[4 * i + 0], j1 = ZZ[4 * i + 1];
    const int j2 = ZZ[4 * i + 2], j3 = ZZ[4 * i + 3];
    float4 v;
    if (QUANT) {
      v.x = rintf(Y[j0] * (1.0f / Qm[j0]));
      v.y = rintf(Y[j1] * (1.0f / Qm[j1]));
      v.z = rintf(Y[j2] * (1.0f / Qm[j2]));
      v.w = rintf(Y[j3] * (1.0f / Qm[j3]));
    } else {
      v = make_float4(Y[j0], Y[j1], Y[j2], Y[j3]);
    }
    const int slot = bx * 128 + bcL * 8 + i8;
    smem[slot ^ (bx & 7)] = v;  // XOR-swizzle: b128 writes hit the 8-cycle floor
  }
  __syncthreads();
#pragma unroll
  for (int it = 0; it < 8; ++it) {
    const int s = it * 256 + t;
    const int bxs = s >> 7;           // which bx cluster
    const int bcLs = (s >> 3) & 15;   // which bc within cluster
    const int is_ = s & 7;            // float4 index within 32-float chunk
    const size_t off =
        (size_t)((by * 16 + bxs) * 1536 + bc0 + bcLs) * 64 + C4 * 32 + is_ * 4;
    *reinterpret_cast<float4*>(outBase + off) = smem[s ^ (bxs & 7)];
  }
  __syncthreads();
}

__global__ __launch_bounds__(256) void jpeg_enc(const float* __restrict__ img,
                                                float* __restrict__ out) {
  __shared__ float4 smem[2048];  // 32 KB staging buffer (reused 4x)

  const int t = threadIdx.x;
  const int w = blockIdx.x;
  const int by = w / 96;           // 0..15 block-row
  const int bc0 = (w % 96) * 16;   // first of 16 consecutive (b*3+c) planes
  const int bx = t & 15;           // block-col (fast across lanes -> coalesced)
  const int bcL = t >> 4;          // local plane index 0..15
  const int bc = bc0 + bcL;

  const float* src = img + (size_t)bc * 16384u + by * 1024u + bx * 8u;

  // Load 8x8 patch (rows are 4x512B contiguous segments per wave), minus 128
  float X[8][8];
#pragma unroll
  for (int r = 0; r < 8; ++r) {
    float4 a = ld4(src + r * 128);
    float4 b = ld4(src + r * 128 + 4);
    X[r][0] = a.x - 128.0f; X[r][1] = a.y - 128.0f;
    X[r][2] = a.z - 128.0f; X[r][3] = a.w - 128.0f;
    X[r][4] = b.x - 128.0f; X[r][5] = b.y - 128.0f;
    X[r][6] = b.z - 128.0f; X[r][7] = b.w - 128.0f;
  }

  // T = D @ X
  float T[8][8];
#pragma unroll
  for (int i = 0; i < 8; ++i) {
#pragma unroll
    for (int l = 0; l < 8; ++l) {
      float s = Dm[i][0] * X[0][l];
#pragma unroll
      for (int k = 1; k < 8; ++k) s = fmaf(Dm[i][k], X[k][l], s);
      T[i][l] = s;
    }
  }

  // Y = T @ D^T
  float Y[64];
#pragma unroll
  for (int i = 0; i < 8; ++i) {
#pragma unroll
    for (int j = 0; j < 8; ++j) {
      float s = T[i][0] * Dm[j][0];
#pragma unroll
      for (int l = 1; l < 8; ++l) s = fmaf(T[i][l], Dm[j][l], s);
      Y[i * 8 + j] = s;
    }
  }

  // Quantized output, then raw DCT output, each in two 32-float halves
  stage_and_drain<true, 0>(Y, smem, out, t, bx, bcL, by, bc0);
  stage_and_drain<true, 1>(Y, smem, out, t, bx, bcL, by, bc0);
  stage_and_drain<false, 0>(Y, smem, out + OUT1, t, bx, bcL, by, bc0);
  stage_and_drain<false, 1>(Y, smem, out + OUT1, t, bx, bcL, by, bc0);
}

extern "C" void kernel_launch(void* const* d_in, const int* in_sizes, int n_in,
                              void* d_out, int out_size, void* d_ws, size_t ws_size,
                              hipStream_t stream) {
  const float* img = (const float*)d_in[0];
  float* out = (float*)d_out;
  // 1536 workgroups: 16 block-rows x 96 bc-groups
  jpeg_enc<<<dim3(1536), dim3(256), 0, stream>>>(img, out);
}